// Round 16
// baseline (388.687 us; speedup 1.0000x reference)
//
#include <hip/hip_runtime.h>
#include <hip/hip_bf16.h>
#include <stdint.h>

// KGTN round 16 = R15 + dataflow crumbs:
// - rn stored IN-PLACE in avn cols 2048:3072 (gates_sum reads nodes_bf
//   there, overwrites same element). h-GEMM becomes single-A split-K x2
//   over contiguous K=3072 ([av_in|av_out|rn] @ W5_full), 2 partials.
// - update_nodes reads n_old from ninit[:,0:1024] (init seeds it);
//   last step skips dead avn/nodesT writes. rn_bf buffer deleted.
// All GEMM configs identical to R15 (family pinned ~640-680 TF; R5/7/11/12
// nulls on schedule micro-opt; R9: no in-kernel cross-block fences).

typedef __attribute__((ext_vector_type(8))) short bf16x8;
typedef __attribute__((ext_vector_type(4))) float f32x4;
typedef __attribute__((ext_vector_type(4))) ushort u16x4;

typedef __attribute__((address_space(3))) void lds_void;
typedef const __attribute__((address_space(1))) void gbl_void;

__device__ __forceinline__ ushort f2b(float v) {
    union { float f; uint32_t u; } c; c.f = v;
    uint32_t u = c.u + 0x7FFFu + ((c.u >> 16) & 1u);   // RNE; inputs finite
    return (ushort)(u >> 16);
}
__device__ __forceinline__ float b2f(ushort u) {
    union { float f; uint32_t i; } c; c.i = ((uint32_t)u) << 16;
    return c.f;
}

#define SB __builtin_amdgcn_sched_barrier(0)

// ---------------- progressive 256x256 kernel (final GEMM) ----------------
// C[M,N] = A[M,K] @ Bt[N,K]^T, fp32 C. Grid (N/256, M/256), 512 threads.
__global__ __launch_bounds__(512) void gemm256b(
    const ushort* __restrict__ A, const ushort* __restrict__ Bt,
    float* __restrict__ C, int K, long lda, long ldb, long ldc)
{
    __shared__ ushort As[2 * 16384];
    __shared__ ushort Bs[2 * 16384];
    const int tid  = threadIdx.x;
    const int lane = tid & 63;
    const int wave = tid >> 6;
    const int wm2  = wave >> 2;
    const int wn4  = wave & 3;

    const int gx  = gridDim.x;
    const int nwg = gx * gridDim.y;
    int h0 = blockIdx.y * gx + blockIdx.x;
    const int bid = (h0 & 7) * (nwg >> 3) + (h0 >> 3);
    const long bm = (long)(bid / gx) * 256;
    const long bn = (long)(bid % gx) * 256;

    const int l15 = lane & 15;
    const int kg  = lane >> 4;
    const int gsw = (lane & 7) ^ (lane >> 3);

    f32x4 acc[2][2][4][2] = {};
    bf16x8 a[4][2], b0[2][2], b1[2][2];

    auto STAGE_HALF = [&](int kt, int which) {
        const bool isA = (which == 0) || (which == 3);
        const int hh = (which >= 2) ? 1 : 0;
        const ushort* src = isA ? A : Bt;
        const long ld   = isA ? lda : ldb;
        const long brow = (isA ? bm : bn) + hh * 128;
        ushort* lds = (isA ? As : Bs) + (kt & 1) * 16384 + hh * 8192;
        const int k0 = kt * 64;
        #pragma unroll
        for (int p = 0; p < 2; ++p) {
            const int slot = wave * 2 + p;
            const int row  = slot * 8 + (lane >> 3);
            const ushort* g = src + (brow + row) * ld + k0 + gsw * 8;
            __builtin_amdgcn_global_load_lds((gbl_void*)g,
                (lds_void*)(lds + slot * 512), 16, 0, 0);
        }
    };

#define LOAD_A(d, qm)                                                        \
    do {                                                                     \
        const ushort* as_ = As + (d) * 16384 + (qm) * 8192;                  \
        _Pragma("unroll")                                                    \
        for (int mi = 0; mi < 4; ++mi) {                                     \
            const int rh = wm2 * 64 + mi * 16 + l15;                         \
            _Pragma("unroll")                                                \
            for (int kk = 0; kk < 2; ++kk) {                                 \
                const int ph_ = (((kk * 4 + kg) ^ (rh & 7)) & 7) * 8;        \
                a[mi][kk] = *(const bf16x8*)(as_ + rh * 64 + ph_);           \
            }                                                                \
        }                                                                    \
    } while (0)

#define LOAD_B(d, qn, breg)                                                  \
    do {                                                                     \
        const ushort* bs_ = Bs + (d) * 16384 + (qn) * 8192;                  \
        _Pragma("unroll")                                                    \
        for (int ni = 0; ni < 2; ++ni) {                                     \
            const int rh = wn4 * 32 + ni * 16 + l15;                         \
            _Pragma("unroll")                                                \
            for (int kk = 0; kk < 2; ++kk) {                                 \
                const int ph_ = (((kk * 4 + kg) ^ (rh & 7)) & 7) * 8;        \
                breg[ni][kk] = *(const bf16x8*)(bs_ + rh * 64 + ph_);        \
            }                                                                \
        }                                                                    \
    } while (0)

#define QUAD(qm, qn, breg)                                                   \
    do {                                                                     \
        __builtin_amdgcn_s_setprio(1);                                       \
        _Pragma("unroll")                                                    \
        for (int kk = 0; kk < 2; ++kk)                                       \
            _Pragma("unroll")                                                \
            for (int mi = 0; mi < 4; ++mi)                                   \
                _Pragma("unroll")                                            \
                for (int ni = 0; ni < 2; ++ni)                               \
                    acc[qm][qn][mi][ni] =                                    \
                        __builtin_amdgcn_mfma_f32_16x16x32_bf16(             \
                            a[mi][kk], breg[ni][kk], acc[qm][qn][mi][ni],    \
                            0, 0, 0);                                        \
        __builtin_amdgcn_s_setprio(0);                                       \
    } while (0)

#define VM(n) do { SB; asm volatile("s_waitcnt vmcnt(" #n ")" ::: "memory"); \
                   SB; __builtin_amdgcn_s_barrier(); SB; } while (0)

    const int KT = K >> 6;
    STAGE_HALF(0, 0); STAGE_HALF(0, 1); STAGE_HALF(0, 2); STAGE_HALF(0, 3);
    for (int kt = 0; kt < KT; ++kt) {
        const int d  = kt & 1;
        const bool nl = (kt + 1 < KT);
        if (nl) { STAGE_HALF(kt + 1, 0); VM(6); } else { VM(4); }
        LOAD_A(d, 0); LOAD_B(d, 0, b0);
        QUAD(0, 0, b0);
        if (nl) { STAGE_HALF(kt + 1, 1); VM(6); } else { VM(2); }
        LOAD_B(d, 1, b1);
        QUAD(0, 1, b1);
        if (nl) { STAGE_HALF(kt + 1, 2); VM(6); } else { VM(0); }
        LOAD_A(d, 1);
        QUAD(1, 1, b1);
        if (nl) STAGE_HALF(kt + 1, 3);
        QUAD(1, 0, b0);
    }
#undef VM

    const int cr0 = (lane >> 4) * 4;
    #pragma unroll
    for (int qm = 0; qm < 2; ++qm)
        #pragma unroll
        for (int qn = 0; qn < 2; ++qn)
            #pragma unroll
            for (int mi = 0; mi < 4; ++mi)
                #pragma unroll
                for (int j = 0; j < 4; ++j) {
                    const long r = bm + qm * 128 + wm2 * 64 + mi * 16 + cr0 + j;
                    #pragma unroll
                    for (int ni = 0; ni < 2; ++ni)
                        C[r * ldc + bn + qn * 128 + wn4 * 32 + ni * 16 + l15] =
                            acc[qm][qn][mi][ni][j];
                }
#undef QUAD
#undef LOAD_B
#undef LOAD_A
}

// ---------------- proven 2-phase GEMM (GGNN path) ----------------
template <int MFR, int EPI>
__global__ __launch_bounds__(256) void gemm_t(
    const ushort* __restrict__ A0, const ushort* __restrict__ A1,
    const ushort* __restrict__ A2, const ushort* __restrict__ Bt,
    void* __restrict__ Cv, int K, long lda01, long lda2, long ldb, long ldc,
    long aKoff, long bKa, long bKk, long cOff, int zdiv)
{
    __shared__ ushort As[2 * MFR * 2048];
    __shared__ ushort Bs[2 * 8192];
    const int tid  = threadIdx.x;
    const int lane = tid & 63;
    const int wave = tid >> 6;
    const int wr = (wave >> 1) * (MFR * 16);
    const int wc = (wave & 1) * 64;

    const int gx  = gridDim.x;
    const int nwg = gx * gridDim.y;
    int h0 = blockIdx.y * gx + blockIdx.x;
    const int bid = (h0 & 7) * (nwg >> 3) + (h0 >> 3);
    const long bm = (long)(bid / gx) * (MFR * 32);
    const long bn = (long)(bid % gx) * 128;

    const int z  = blockIdx.z;
    const int zA = z / zdiv;
    const int zK = z - zA * zdiv;
    const ushort* A  = ((zA == 0) ? A0 : (zA == 1) ? A1 : A2) + (long)zK * aKoff;
    const long lda   = (zA == 2) ? lda2 : lda01;
    const ushort* Bp = Bt + (long)zA * bKa + (long)zK * bKk;

    const int l15  = lane & 15;
    const int kg   = lane >> 4;
    const int srow = lane >> 3;
    const int gsw  = ((lane & 7) ^ srow) & 7;

    f32x4 acc[MFR][4] = {};

    auto STAGE = [&](int k0, int buf) {
        #pragma unroll
        for (int p = 0; p < MFR; ++p) {
            const int slot = wave * MFR + p;
            const int row  = slot * 8 + srow;
            const ushort* ga = A + (bm + row) * lda + (k0 + gsw * 8);
            __builtin_amdgcn_global_load_lds((gbl_void*)ga,
                (lds_void*)(As + buf * MFR * 2048 + slot * 512), 16, 0, 0);
        }
        #pragma unroll
        for (int p = 0; p < 4; ++p) {
            const int slot = wave * 4 + p;
            const int row  = slot * 8 + srow;
            const ushort* gb = Bp + (bn + row) * ldb + (k0 + gsw * 8);
            __builtin_amdgcn_global_load_lds((gbl_void*)gb,
                (lds_void*)(Bs + buf * 8192 + slot * 512), 16, 0, 0);
        }
    };

    auto COMPUTE = [&](int buf) {
        const ushort* as = As + buf * MFR * 2048;
        const ushort* bs = Bs + buf * 8192;
        #pragma unroll
        for (int kk = 0; kk < 2; ++kk) {
            const int ph = (((kk * 4 + kg) ^ (lane & 7)) & 7) * 8;
            bf16x8 af[MFR], bv[4];
            #pragma unroll
            for (int m = 0; m < MFR; ++m)
                af[m] = *(const bf16x8*)(as + (wr + m * 16 + l15) * 64 + ph);
            #pragma unroll
            for (int n = 0; n < 4; ++n)
                bv[n] = *(const bf16x8*)(bs + (wc + n * 16 + l15) * 64 + ph);
            __builtin_amdgcn_s_setprio(1);
            #pragma unroll
            for (int m = 0; m < MFR; ++m)
                #pragma unroll
                for (int n = 0; n < 4; ++n)
                    acc[m][n] = __builtin_amdgcn_mfma_f32_16x16x32_bf16(
                        af[m], bv[n], acc[m][n], 0, 0, 0);
            __builtin_amdgcn_s_setprio(0);
        }
    };

#define SYNC()                                              \
    __builtin_amdgcn_sched_barrier(0);                      \
    asm volatile("s_waitcnt vmcnt(0)" ::: "memory");        \
    __builtin_amdgcn_s_barrier();                           \
    __builtin_amdgcn_sched_barrier(0)

    const int T = K >> 6;
    STAGE(0, 0);
    for (int t = 0; t < T; ++t) {
        SYNC();
        if (t + 1 < T) STAGE((t + 1) * 64, (t + 1) & 1);
        COMPUTE(t & 1);
    }
#undef SYNC

    const int cr0 = (lane >> 4) * 4;
    #pragma unroll
    for (int m = 0; m < MFR; ++m) {
        #pragma unroll
        for (int j = 0; j < 4; ++j) {
            const long r = bm + wr + m * 16 + cr0 + j;
            #pragma unroll
            for (int n = 0; n < 4; ++n) {
                const long c = bn + wc + n * 16 + l15;
                if (EPI == 0)
                    ((float*)Cv + cOff * z)[r * ldc + c] = acc[m][n][j];
                else
                    ((ushort*)Cv + cOff * z)[r * ldc + c] = f2b(acc[m][n][j]);
            }
        }
    }
}

// zv_bf = sigmoid(zp0+zp1); rn written IN-PLACE over nodes_bf in avn
// cols 2048:3072 (read then overwrite, same thread/element).
__global__ __launch_bounds__(256) void gates_sum_k(const ushort* __restrict__ p,
        ushort* __restrict__ avn, ushort* __restrict__ zv) {
    const long i = (long)blockIdx.x * 256 + threadIdx.x;
    const long r = i >> 8, c = (i & 255) << 2;
    const long base = r * 2048 + c;
    u16x4 z0 = *(const u16x4*)(p + base);
    u16x4 z1 = *(const u16x4*)(p + 4194304 + base);
    u16x4 r0 = *(const u16x4*)(p + base + 1024);
    u16x4 r1 = *(const u16x4*)(p + 4194304 + base + 1024);
    u16x4 nd = *(const u16x4*)(avn + r * 3072 + 2048 + c);
    u16x4 zo, ro;
    #pragma unroll
    for (int j = 0; j < 4; ++j) {
        zo[j] = f2b(1.f / (1.f + __expf(-(b2f(z0[j]) + b2f(z1[j])))));
        ro[j] = f2b(b2f(nd[j]) / (1.f + __expf(-(b2f(r0[j]) + b2f(r1[j])))));
    }
    *(u16x4*)(zv + r * 1024 + c) = zo;
    *(u16x4*)(avn + r * 3072 + 2048 + c) = ro;
}

__global__ __launch_bounds__(256) void cvt_bf16_k(const float* __restrict__ src,
                                                  ushort* __restrict__ dst, long n4) {
    long i = (long)blockIdx.x * 256 + threadIdx.x;
    if (i >= n4) return;
    f32x4 v = *(const f32x4*)(src + i * 4);
    u16x4 o;
    #pragma unroll
    for (int j = 0; j < 4; ++j) o[j] = f2b(v[j]);
    *(u16x4*)(dst + i * 4) = o;
}

__global__ __launch_bounds__(256) void inM_dual_k(const float* __restrict__ src,
        ushort* __restrict__ dst, ushort* __restrict__ dstT) {
    __shared__ float t[32][33];
    const int c0 = blockIdx.x * 32, r0 = blockIdx.y * 32;
    const int tx = threadIdx.x & 31, ty = threadIdx.x >> 5;
    #pragma unroll
    for (int i = 0; i < 32; i += 8) {
        const float v = src[(long)(r0 + ty + i) * 2048 + c0 + tx];
        dst[(long)(r0 + ty + i) * 2048 + c0 + tx] = f2b(v);
        t[ty + i][tx] = v;
    }
    __syncthreads();
    #pragma unroll
    for (int i = 0; i < 32; i += 8)
        dstT[(long)(c0 + ty + i) * 2048 + r0 + tx] = f2b(t[tx][ty + i]);
}

// Fused weight transposes (z=0..6).
__global__ __launch_bounds__(256) void wprep_k(const float* __restrict__ w3,
        const float* __restrict__ w4, const float* __restrict__ w5,
        const float* __restrict__ u3, const float* __restrict__ u4,
        const float* __restrict__ u5, const float* __restrict__ fcw,
        ushort* __restrict__ Wzr, ushort* __restrict__ W5t,
        ushort* __restrict__ fcw_t) {
    const int zz = blockIdx.z;
    if (zz >= 3 && zz < 6 && blockIdx.y >= 32) return;
    const float* src;
    ushort* dst;
    long dld;
    switch (zz) {
        case 0: src = w3;  dst = Wzr;                    dld = 3072; break;
        case 1: src = w4;  dst = Wzr + 3145728l;         dld = 3072; break;
        case 2: src = w5;  dst = W5t;                    dld = 3072; break;
        case 3: src = u3;  dst = Wzr + 2048;             dld = 3072; break;
        case 4: src = u4;  dst = Wzr + 3145728l + 2048;  dld = 3072; break;
        case 5: src = u5;  dst = W5t + 2048;             dld = 3072; break;
        default: src = fcw; dst = fcw_t;                 dld = 2048; break;
    }
    __shared__ float t[32][33];
    const int c0 = blockIdx.x * 32, r0 = blockIdx.y * 32;
    const int tx = threadIdx.x & 31, ty = threadIdx.x >> 5;
    #pragma unroll
    for (int i = 0; i < 32; i += 8)
        t[ty + i][tx] = src[(long)(r0 + ty + i) * 1024 + c0 + tx];
    __syncthreads();
    #pragma unroll
    for (int i = 0; i < 32; i += 8)
        dst[(long)(c0 + ty + i) * dld + r0 + tx] = f2b(t[tx][ty + i]);
}

// init: nodesT_bf; nodes_bf -> avn cols 2048:3072, ninit cols 0:1024 AND
// init_bf -> ninit cols 1024:2048.
__global__ __launch_bounds__(256) void init_nodes_k(const float* __restrict__ lfw,
        ushort* __restrict__ nodesT, ushort* __restrict__ avn,
        ushort* __restrict__ ninit) {
    __shared__ float t[32][33];
    const int n0 = blockIdx.x * 32, h0 = blockIdx.y * 32;
    const int tx = threadIdx.x & 31, ty = threadIdx.x >> 5;
    #pragma unroll
    for (int i = 0; i < 32; i += 8) {
        float v = lfw[(long)(h0 + ty + i) * 2048 + n0 + tx];
        nodesT[(long)(h0 + ty + i) * 2048 + n0 + tx] = f2b(v);
        t[ty + i][tx] = v;
    }
    __syncthreads();
    #pragma unroll
    for (int i = 0; i < 32; i += 8) {
        const int n = n0 + ty + i, hh = h0 + tx;
        ushort b = f2b(t[tx][ty + i]);
        avn[(long)n * 3072 + 2048 + hh] = b;
        ninit[(long)n * 2048 + hh] = b;
        ninit[(long)n * 2048 + 1024 + hh] = b;
    }
}

// nodes_new = (1-z)*n_old + z*tanh(hp0+hp1); n_old from ninit[:,0:1024]
// (read then overwritten by same thread). LAST skips dead avn/nodesT writes.
template <bool LAST>
__global__ __launch_bounds__(256) void update_nodes_k(
        const ushort* __restrict__ zv, const ushort* __restrict__ hp,
        ushort* __restrict__ avn, ushort* __restrict__ ninit,
        ushort* __restrict__ nodesT) {
    __shared__ float t[32][33];
    const int c0 = blockIdx.x * 32, r0 = blockIdx.y * 32;
    const int tx = threadIdx.x & 31, ty = threadIdx.x >> 5;
    #pragma unroll
    for (int i = 0; i < 32; i += 8) {
        const int r = r0 + ty + i, c = c0 + tx;
        const long idx = (long)r * 1024 + c;
        const float z = b2f(zv[idx]);
        const float n_old = b2f(ninit[(long)r * 2048 + c]);
        const float hsum = b2f(hp[idx]) + b2f(hp[idx + 2097152]);
        const float nn = (1.f - z) * n_old + z * tanhf(hsum);
        const ushort b = f2b(nn);
        ninit[(long)r * 2048 + c] = b;
        if (!LAST) {
            avn[(long)r * 3072 + 2048 + c] = b;
            t[ty + i][tx] = nn;
        }
    }
    if (!LAST) {
        __syncthreads();
        #pragma unroll
        for (int i = 0; i < 32; i += 8)
            nodesT[(long)(c0 + ty + i) * 2048 + r0 + tx] = f2b(t[tx][ty + i]);
    }
}

// v = sop0+sop1+bias (sop bf16); so_bf = bf16(v); partial sums of v^2.
__global__ __launch_bounds__(256) void bias_l2(const ushort* __restrict__ s,
        const float* __restrict__ bias, ushort* __restrict__ so_bf,
        float* __restrict__ partials) {
    __shared__ float red[256];
    const int tid = threadIdx.x;
    const long base = (long)blockIdx.x * 2048;
    float sum = 0.f;
    #pragma unroll
    for (int it = 0; it < 8; ++it) {
        const long i = base + tid + it * 256;
        const float v = b2f(s[i]) + b2f(s[i + 2097152]) + bias[i & 1023];
        so_bf[i] = f2b(v);
        sum += v * v;
    }
    red[tid] = sum;
    __syncthreads();
    #pragma unroll
    for (int w = 128; w > 0; w >>= 1) {
        if (tid < w) red[tid] += red[tid + w];
        __syncthreads();
    }
    if (tid == 0) partials[blockIdx.x] = red[0];
}

__global__ __launch_bounds__(256) void reduce_final(const float* __restrict__ partials,
                                                    float* __restrict__ out) {
    __shared__ float red[256];
    const int tid = threadIdx.x;
    red[tid] = partials[tid] + partials[tid + 256] + partials[tid + 512] + partials[tid + 768];
    __syncthreads();
    #pragma unroll
    for (int w = 128; w > 0; w >>= 1) {
        if (tid < w) red[tid] += red[tid + w];
        __syncthreads();
    }
    if (tid == 0) out[0] = red[0];
}

extern "C" void kernel_launch(void* const* d_in, const int* in_sizes, int n_in,
                              void* d_out, int out_size, void* d_ws, size_t ws_size,
                              hipStream_t stream) {
    const float* x   = (const float*)d_in[0];
    const float* lfw = (const float*)d_in[1];
    const float* inM = (const float*)d_in[2];
    const float* w3w = (const float*)d_in[3];
    const float* w3u = (const float*)d_in[4];
    const float* w4w = (const float*)d_in[5];
    const float* w4u = (const float*)d_in[6];
    const float* w5w = (const float*)d_in[7];
    const float* w5u = (const float*)d_in[8];
    const float* fcw = (const float*)d_in[9];
    const float* fcb = (const float*)d_in[10];
    float* out = (float*)d_out;

    const int B = 8192, N = 2048;
    const long NH = 2097152;

    ushort* zrp  = (ushort*)out;        // 2x [2048,2048] bf16 scratch
    ushort* hpre = (ushort*)out;        // 2x [2048,1024] bf16
    ushort* sop  = (ushort*)out;        // 2x [2048,1024] bf16

    char* p = (char*)d_ws;
    auto alloc = [&](size_t bytes) {
        char* r = p; p += (bytes + 255) & ~(size_t)255; return r;
    };
    float*  partials = (float*)alloc(1024 * 4);
    ushort* zv       = (ushort*)alloc(NH * 2);
    ushort* avn      = (ushort*)alloc(6291456ull * 2);
    ushort* nodesT   = (ushort*)alloc(NH * 2);
    ushort* ninit    = (ushort*)alloc(4194304ull * 2);
    ushort* inM_bf   = (ushort*)alloc(4194304ull * 2);
    ushort* inMT_bf  = (ushort*)alloc(4194304ull * 2);
    ushort* Wzr_t    = (ushort*)alloc(6291456ull * 2);
    ushort* W5_t     = (ushort*)alloc(3145728ull * 2);
    ushort* fcw_t    = (ushort*)alloc(NH * 2);
    ushort* x_bf     = (ushort*)alloc(8388608ull * 2);
    ushort* so_bf    = (ushort*)alloc(NH * 2);

    const dim3 tb(256);

    // ---- prep ----
    cvt_bf16_k<<<8192, tb, 0, stream>>>(x, x_bf, 2097152);
    inM_dual_k<<<dim3(64, 64), tb, 0, stream>>>(inM, inM_bf, inMT_bf);
    wprep_k<<<dim3(32, 64, 7), tb, 0, stream>>>(w3w, w4w, w5w, w3u, w4u, w5u,
                                                fcw, Wzr_t, W5_t, fcw_t);
    init_nodes_k<<<dim3(64, 32), tb, 0, stream>>>(lfw, nodesT, avn, ninit);

    // ---- GGNN time steps ----
    for (int t = 0; t < 3; ++t) {
        // avn[:, z*1024:+1024] = bf16( (z?inMT:inM) @ nodes ), direct epi
        gemm_t<2, 1><<<dim3(8, 32, 2), tb, 0, stream>>>(
            inM_bf, inMT_bf, nullptr, nodesT, avn,
            2048, 2048, 0, 2048, 3072,
            0, 0, 0, 1024, 1);
        // zr bf16 partials: split-K x2 over K=3072 (avn cols 2048:3072 = nodes)
        gemm_t<4, 1><<<dim3(16, 16, 2), tb, 0, stream>>>(
            avn, nullptr, nullptr, Wzr_t, zrp,
            1536, 3072, 0, 3072, 2048,
            1536, 0, 1536, 4194304, 2);
        // zv; rn overwrites avn cols 2048:3072 in-place
        gates_sum_k<<<2048, tb, 0, stream>>>(zrp, avn, zv);
        // hpre bf16 partials: single-A split-K x2 over K=3072 ([av|rn] @ W5)
        gemm_t<2, 1><<<dim3(8, 32, 2), tb, 0, stream>>>(
            avn, nullptr, nullptr, W5_t, hpre,
            1536, 3072, 0, 3072, 1024,
            1536, 0, 1536, 2097152, 2);
        if (t < 2)
            update_nodes_k<false><<<dim3(32, 64), tb, 0, stream>>>(
                zv, hpre, avn, ninit, nodesT);
        else
            update_nodes_k<true><<<dim3(32, 64), tb, 0, stream>>>(
                zv, hpre, avn, ninit, nodesT);
    }

    // step_out bf16 partials = [nodes|init] @ fc_out_w
    gemm_t<2, 1><<<dim3(8, 32, 2), tb, 0, stream>>>(
        ninit, ninit + 1024, nullptr, fcw_t, sop,
        1024, 2048, 0, 2048, 1024,
        0, 1024, 0, 2097152, 1);
    bias_l2<<<1024, tb, 0, stream>>>(sop, fcb, so_bf, partials);
    reduce_final<<<1, tb, 0, stream>>>(partials, out + (long)B * N);
    // output = x @ step_out^T : progressive 256x256 kernel
    gemm256b<<<dim3(8, 32), 512, 0, stream>>>(x_bf, so_bf, out,
                                              1024, 1024, 1024, 2048);
}

// Round 17
// 381.017 us; speedup vs baseline: 1.0201x; 1.0201x over previous
//
#include <hip/hip_runtime.h>
#include <hip/hip_bf16.h>
#include <stdint.h>

// KGTN round 17 = R16 with h-GEMM reverted to 3-way zA split (768 blocks,
// K=1024 each) — R16's 512-block single-A form lost ~2.5us of block
// parallelism. The 3 A-pointers now index into avn directly (rn in-place
// at cols 2048:3072), keeping R16's buffer simplification.
// Lesson bank: GEMM family at K=1024-3072 is pinned ~645-680 TF (m102
// shape-curve regime, 5 schedule nulls); no in-kernel cross-block fences
// (R9); row-major XCD chunking for A-dominant GEMMs (R8).

typedef __attribute__((ext_vector_type(8))) short bf16x8;
typedef __attribute__((ext_vector_type(4))) float f32x4;
typedef __attribute__((ext_vector_type(4))) ushort u16x4;

typedef __attribute__((address_space(3))) void lds_void;
typedef const __attribute__((address_space(1))) void gbl_void;

__device__ __forceinline__ ushort f2b(float v) {
    union { float f; uint32_t u; } c; c.f = v;
    uint32_t u = c.u + 0x7FFFu + ((c.u >> 16) & 1u);   // RNE; inputs finite
    return (ushort)(u >> 16);
}
__device__ __forceinline__ float b2f(ushort u) {
    union { float f; uint32_t i; } c; c.i = ((uint32_t)u) << 16;
    return c.f;
}

#define SB __builtin_amdgcn_sched_barrier(0)

// ---------------- progressive 256x256 kernel (final GEMM) ----------------
// C[M,N] = A[M,K] @ Bt[N,K]^T, fp32 C. Grid (N/256, M/256), 512 threads.
__global__ __launch_bounds__(512) void gemm256b(
    const ushort* __restrict__ A, const ushort* __restrict__ Bt,
    float* __restrict__ C, int K, long lda, long ldb, long ldc)
{
    __shared__ ushort As[2 * 16384];
    __shared__ ushort Bs[2 * 16384];
    const int tid  = threadIdx.x;
    const int lane = tid & 63;
    const int wave = tid >> 6;
    const int wm2  = wave >> 2;
    const int wn4  = wave & 3;

    const int gx  = gridDim.x;
    const int nwg = gx * gridDim.y;
    int h0 = blockIdx.y * gx + blockIdx.x;
    const int bid = (h0 & 7) * (nwg >> 3) + (h0 >> 3);
    const long bm = (long)(bid / gx) * 256;
    const long bn = (long)(bid % gx) * 256;

    const int l15 = lane & 15;
    const int kg  = lane >> 4;
    const int gsw = (lane & 7) ^ (lane >> 3);

    f32x4 acc[2][2][4][2] = {};
    bf16x8 a[4][2], b0[2][2], b1[2][2];

    auto STAGE_HALF = [&](int kt, int which) {
        const bool isA = (which == 0) || (which == 3);
        const int hh = (which >= 2) ? 1 : 0;
        const ushort* src = isA ? A : Bt;
        const long ld   = isA ? lda : ldb;
        const long brow = (isA ? bm : bn) + hh * 128;
        ushort* lds = (isA ? As : Bs) + (kt & 1) * 16384 + hh * 8192;
        const int k0 = kt * 64;
        #pragma unroll
        for (int p = 0; p < 2; ++p) {
            const int slot = wave * 2 + p;
            const int row  = slot * 8 + (lane >> 3);
            const ushort* g = src + (brow + row) * ld + k0 + gsw * 8;
            __builtin_amdgcn_global_load_lds((gbl_void*)g,
                (lds_void*)(lds + slot * 512), 16, 0, 0);
        }
    };

#define LOAD_A(d, qm)                                                        \
    do {                                                                     \
        const ushort* as_ = As + (d) * 16384 + (qm) * 8192;                  \
        _Pragma("unroll")                                                    \
        for (int mi = 0; mi < 4; ++mi) {                                     \
            const int rh = wm2 * 64 + mi * 16 + l15;                         \
            _Pragma("unroll")                                                \
            for (int kk = 0; kk < 2; ++kk) {                                 \
                const int ph_ = (((kk * 4 + kg) ^ (rh & 7)) & 7) * 8;        \
                a[mi][kk] = *(const bf16x8*)(as_ + rh * 64 + ph_);           \
            }                                                                \
        }                                                                    \
    } while (0)

#define LOAD_B(d, qn, breg)                                                  \
    do {                                                                     \
        const ushort* bs_ = Bs + (d) * 16384 + (qn) * 8192;                  \
        _Pragma("unroll")                                                    \
        for (int ni = 0; ni < 2; ++ni) {                                     \
            const int rh = wn4 * 32 + ni * 16 + l15;                         \
            _Pragma("unroll")                                                \
            for (int kk = 0; kk < 2; ++kk) {                                 \
                const int ph_ = (((kk * 4 + kg) ^ (rh & 7)) & 7) * 8;        \
                breg[ni][kk] = *(const bf16x8*)(bs_ + rh * 64 + ph_);        \
            }                                                                \
        }                                                                    \
    } while (0)

#define QUAD(qm, qn, breg)                                                   \
    do {                                                                     \
        __builtin_amdgcn_s_setprio(1);                                       \
        _Pragma("unroll")                                                    \
        for (int kk = 0; kk < 2; ++kk)                                       \
            _Pragma("unroll")                                                \
            for (int mi = 0; mi < 4; ++mi)                                   \
                _Pragma("unroll")                                            \
                for (int ni = 0; ni < 2; ++ni)                               \
                    acc[qm][qn][mi][ni] =                                    \
                        __builtin_amdgcn_mfma_f32_16x16x32_bf16(             \
                            a[mi][kk], breg[ni][kk], acc[qm][qn][mi][ni],    \
                            0, 0, 0);                                        \
        __builtin_amdgcn_s_setprio(0);                                       \
    } while (0)

#define VM(n) do { SB; asm volatile("s_waitcnt vmcnt(" #n ")" ::: "memory"); \
                   SB; __builtin_amdgcn_s_barrier(); SB; } while (0)

    const int KT = K >> 6;
    STAGE_HALF(0, 0); STAGE_HALF(0, 1); STAGE_HALF(0, 2); STAGE_HALF(0, 3);
    for (int kt = 0; kt < KT; ++kt) {
        const int d  = kt & 1;
        const bool nl = (kt + 1 < KT);
        if (nl) { STAGE_HALF(kt + 1, 0); VM(6); } else { VM(4); }
        LOAD_A(d, 0); LOAD_B(d, 0, b0);
        QUAD(0, 0, b0);
        if (nl) { STAGE_HALF(kt + 1, 1); VM(6); } else { VM(2); }
        LOAD_B(d, 1, b1);
        QUAD(0, 1, b1);
        if (nl) { STAGE_HALF(kt + 1, 2); VM(6); } else { VM(0); }
        LOAD_A(d, 1);
        QUAD(1, 1, b1);
        if (nl) STAGE_HALF(kt + 1, 3);
        QUAD(1, 0, b0);
    }
#undef VM

    const int cr0 = (lane >> 4) * 4;
    #pragma unroll
    for (int qm = 0; qm < 2; ++qm)
        #pragma unroll
        for (int qn = 0; qn < 2; ++qn)
            #pragma unroll
            for (int mi = 0; mi < 4; ++mi)
                #pragma unroll
                for (int j = 0; j < 4; ++j) {
                    const long r = bm + qm * 128 + wm2 * 64 + mi * 16 + cr0 + j;
                    #pragma unroll
                    for (int ni = 0; ni < 2; ++ni)
                        C[r * ldc + bn + qn * 128 + wn4 * 32 + ni * 16 + l15] =
                            acc[qm][qn][mi][ni][j];
                }
#undef QUAD
#undef LOAD_B
#undef LOAD_A
}

// ---------------- proven 2-phase GEMM (GGNN path) ----------------
template <int MFR, int EPI>
__global__ __launch_bounds__(256) void gemm_t(
    const ushort* __restrict__ A0, const ushort* __restrict__ A1,
    const ushort* __restrict__ A2, const ushort* __restrict__ Bt,
    void* __restrict__ Cv, int K, long lda01, long lda2, long ldb, long ldc,
    long aKoff, long bKa, long bKk, long cOff, int zdiv)
{
    __shared__ ushort As[2 * MFR * 2048];
    __shared__ ushort Bs[2 * 8192];
    const int tid  = threadIdx.x;
    const int lane = tid & 63;
    const int wave = tid >> 6;
    const int wr = (wave >> 1) * (MFR * 16);
    const int wc = (wave & 1) * 64;

    const int gx  = gridDim.x;
    const int nwg = gx * gridDim.y;
    int h0 = blockIdx.y * gx + blockIdx.x;
    const int bid = (h0 & 7) * (nwg >> 3) + (h0 >> 3);
    const long bm = (long)(bid / gx) * (MFR * 32);
    const long bn = (long)(bid % gx) * 128;

    const int z  = blockIdx.z;
    const int zA = z / zdiv;
    const int zK = z - zA * zdiv;
    const ushort* A  = ((zA == 0) ? A0 : (zA == 1) ? A1 : A2) + (long)zK * aKoff;
    const long lda   = (zA == 2) ? lda2 : lda01;
    const ushort* Bp = Bt + (long)zA * bKa + (long)zK * bKk;

    const int l15  = lane & 15;
    const int kg   = lane >> 4;
    const int srow = lane >> 3;
    const int gsw  = ((lane & 7) ^ srow) & 7;

    f32x4 acc[MFR][4] = {};

    auto STAGE = [&](int k0, int buf) {
        #pragma unroll
        for (int p = 0; p < MFR; ++p) {
            const int slot = wave * MFR + p;
            const int row  = slot * 8 + srow;
            const ushort* ga = A + (bm + row) * lda + (k0 + gsw * 8);
            __builtin_amdgcn_global_load_lds((gbl_void*)ga,
                (lds_void*)(As + buf * MFR * 2048 + slot * 512), 16, 0, 0);
        }
        #pragma unroll
        for (int p = 0; p < 4; ++p) {
            const int slot = wave * 4 + p;
            const int row  = slot * 8 + srow;
            const ushort* gb = Bp + (bn + row) * ldb + (k0 + gsw * 8);
            __builtin_amdgcn_global_load_lds((gbl_void*)gb,
                (lds_void*)(Bs + buf * 8192 + slot * 512), 16, 0, 0);
        }
    };

    auto COMPUTE = [&](int buf) {
        const ushort* as = As + buf * MFR * 2048;
        const ushort* bs = Bs + buf * 8192;
        #pragma unroll
        for (int kk = 0; kk < 2; ++kk) {
            const int ph = (((kk * 4 + kg) ^ (lane & 7)) & 7) * 8;
            bf16x8 af[MFR], bv[4];
            #pragma unroll
            for (int m = 0; m < MFR; ++m)
                af[m] = *(const bf16x8*)(as + (wr + m * 16 + l15) * 64 + ph);
            #pragma unroll
            for (int n = 0; n < 4; ++n)
                bv[n] = *(const bf16x8*)(bs + (wc + n * 16 + l15) * 64 + ph);
            __builtin_amdgcn_s_setprio(1);
            #pragma unroll
            for (int m = 0; m < MFR; ++m)
                #pragma unroll
                for (int n = 0; n < 4; ++n)
                    acc[m][n] = __builtin_amdgcn_mfma_f32_16x16x32_bf16(
                        af[m], bv[n], acc[m][n], 0, 0, 0);
            __builtin_amdgcn_s_setprio(0);
        }
    };

#define SYNC()                                              \
    __builtin_amdgcn_sched_barrier(0);                      \
    asm volatile("s_waitcnt vmcnt(0)" ::: "memory");        \
    __builtin_amdgcn_s_barrier();                           \
    __builtin_amdgcn_sched_barrier(0)

    const int T = K >> 6;
    STAGE(0, 0);
    for (int t = 0; t < T; ++t) {
        SYNC();
        if (t + 1 < T) STAGE((t + 1) * 64, (t + 1) & 1);
        COMPUTE(t & 1);
    }
#undef SYNC

    const int cr0 = (lane >> 4) * 4;
    #pragma unroll
    for (int m = 0; m < MFR; ++m) {
        #pragma unroll
        for (int j = 0; j < 4; ++j) {
            const long r = bm + wr + m * 16 + cr0 + j;
            #pragma unroll
            for (int n = 0; n < 4; ++n) {
                const long c = bn + wc + n * 16 + l15;
                if (EPI == 0)
                    ((float*)Cv + cOff * z)[r * ldc + c] = acc[m][n][j];
                else
                    ((ushort*)Cv + cOff * z)[r * ldc + c] = f2b(acc[m][n][j]);
            }
        }
    }
}

// zv_bf = sigmoid(zp0+zp1); rn written IN-PLACE over nodes_bf in avn
// cols 2048:3072 (read then overwrite, same thread/element).
__global__ __launch_bounds__(256) void gates_sum_k(const ushort* __restrict__ p,
        ushort* __restrict__ avn, ushort* __restrict__ zv) {
    const long i = (long)blockIdx.x * 256 + threadIdx.x;
    const long r = i >> 8, c = (i & 255) << 2;
    const long base = r * 2048 + c;
    u16x4 z0 = *(const u16x4*)(p + base);
    u16x4 z1 = *(const u16x4*)(p + 4194304 + base);
    u16x4 r0 = *(const u16x4*)(p + base + 1024);
    u16x4 r1 = *(const u16x4*)(p + 4194304 + base + 1024);
    u16x4 nd = *(const u16x4*)(avn + r * 3072 + 2048 + c);
    u16x4 zo, ro;
    #pragma unroll
    for (int j = 0; j < 4; ++j) {
        zo[j] = f2b(1.f / (1.f + __expf(-(b2f(z0[j]) + b2f(z1[j])))));
        ro[j] = f2b(b2f(nd[j]) / (1.f + __expf(-(b2f(r0[j]) + b2f(r1[j])))));
    }
    *(u16x4*)(zv + r * 1024 + c) = zo;
    *(u16x4*)(avn + r * 3072 + 2048 + c) = ro;
}

__global__ __launch_bounds__(256) void cvt_bf16_k(const float* __restrict__ src,
                                                  ushort* __restrict__ dst, long n4) {
    long i = (long)blockIdx.x * 256 + threadIdx.x;
    if (i >= n4) return;
    f32x4 v = *(const f32x4*)(src + i * 4);
    u16x4 o;
    #pragma unroll
    for (int j = 0; j < 4; ++j) o[j] = f2b(v[j]);
    *(u16x4*)(dst + i * 4) = o;
}

__global__ __launch_bounds__(256) void inM_dual_k(const float* __restrict__ src,
        ushort* __restrict__ dst, ushort* __restrict__ dstT) {
    __shared__ float t[32][33];
    const int c0 = blockIdx.x * 32, r0 = blockIdx.y * 32;
    const int tx = threadIdx.x & 31, ty = threadIdx.x >> 5;
    #pragma unroll
    for (int i = 0; i < 32; i += 8) {
        const float v = src[(long)(r0 + ty + i) * 2048 + c0 + tx];
        dst[(long)(r0 + ty + i) * 2048 + c0 + tx] = f2b(v);
        t[ty + i][tx] = v;
    }
    __syncthreads();
    #pragma unroll
    for (int i = 0; i < 32; i += 8)
        dstT[(long)(c0 + ty + i) * 2048 + r0 + tx] = f2b(t[tx][ty + i]);
}

// Fused weight transposes (z=0..6).
__global__ __launch_bounds__(256) void wprep_k(const float* __restrict__ w3,
        const float* __restrict__ w4, const float* __restrict__ w5,
        const float* __restrict__ u3, const float* __restrict__ u4,
        const float* __restrict__ u5, const float* __restrict__ fcw,
        ushort* __restrict__ Wzr, ushort* __restrict__ W5t,
        ushort* __restrict__ fcw_t) {
    const int zz = blockIdx.z;
    if (zz >= 3 && zz < 6 && blockIdx.y >= 32) return;
    const float* src;
    ushort* dst;
    long dld;
    switch (zz) {
        case 0: src = w3;  dst = Wzr;                    dld = 3072; break;
        case 1: src = w4;  dst = Wzr + 3145728l;         dld = 3072; break;
        case 2: src = w5;  dst = W5t;                    dld = 3072; break;
        case 3: src = u3;  dst = Wzr + 2048;             dld = 3072; break;
        case 4: src = u4;  dst = Wzr + 3145728l + 2048;  dld = 3072; break;
        case 5: src = u5;  dst = W5t + 2048;             dld = 3072; break;
        default: src = fcw; dst = fcw_t;                 dld = 2048; break;
    }
    __shared__ float t[32][33];
    const int c0 = blockIdx.x * 32, r0 = blockIdx.y * 32;
    const int tx = threadIdx.x & 31, ty = threadIdx.x >> 5;
    #pragma unroll
    for (int i = 0; i < 32; i += 8)
        t[ty + i][tx] = src[(long)(r0 + ty + i) * 1024 + c0 + tx];
    __syncthreads();
    #pragma unroll
    for (int i = 0; i < 32; i += 8)
        dst[(long)(c0 + ty + i) * dld + r0 + tx] = f2b(t[tx][ty + i]);
}

// init: nodesT_bf; nodes_bf -> avn cols 2048:3072, ninit cols 0:1024 AND
// init_bf -> ninit cols 1024:2048.
__global__ __launch_bounds__(256) void init_nodes_k(const float* __restrict__ lfw,
        ushort* __restrict__ nodesT, ushort* __restrict__ avn,
        ushort* __restrict__ ninit) {
    __shared__ float t[32][33];
    const int n0 = blockIdx.x * 32, h0 = blockIdx.y * 32;
    const int tx = threadIdx.x & 31, ty = threadIdx.x >> 5;
    #pragma unroll
    for (int i = 0; i < 32; i += 8) {
        float v = lfw[(long)(h0 + ty + i) * 2048 + n0 + tx];
        nodesT[(long)(h0 + ty + i) * 2048 + n0 + tx] = f2b(v);
        t[ty + i][tx] = v;
    }
    __syncthreads();
    #pragma unroll
    for (int i = 0; i < 32; i += 8) {
        const int n = n0 + ty + i, hh = h0 + tx;
        ushort b = f2b(t[tx][ty + i]);
        avn[(long)n * 3072 + 2048 + hh] = b;
        ninit[(long)n * 2048 + hh] = b;
        ninit[(long)n * 2048 + 1024 + hh] = b;
    }
}

// nodes_new = (1-z)*n_old + z*tanh(hp0+hp1+hp2); n_old from ninit[:,0:1024]
// (read then overwritten by same thread). LAST skips dead avn/nodesT writes.
template <bool LAST>
__global__ __launch_bounds__(256) void update_nodes_k(
        const ushort* __restrict__ zv, const ushort* __restrict__ hp,
        ushort* __restrict__ avn, ushort* __restrict__ ninit,
        ushort* __restrict__ nodesT) {
    __shared__ float t[32][33];
    const int c0 = blockIdx.x * 32, r0 = blockIdx.y * 32;
    const int tx = threadIdx.x & 31, ty = threadIdx.x >> 5;
    #pragma unroll
    for (int i = 0; i < 32; i += 8) {
        const int r = r0 + ty + i, c = c0 + tx;
        const long idx = (long)r * 1024 + c;
        const float z = b2f(zv[idx]);
        const float n_old = b2f(ninit[(long)r * 2048 + c]);
        const float hsum = b2f(hp[idx]) + b2f(hp[idx + 2097152])
                         + b2f(hp[idx + 4194304]);
        const float nn = (1.f - z) * n_old + z * tanhf(hsum);
        const ushort b = f2b(nn);
        ninit[(long)r * 2048 + c] = b;
        if (!LAST) {
            avn[(long)r * 3072 + 2048 + c] = b;
            t[ty + i][tx] = nn;
        }
    }
    if (!LAST) {
        __syncthreads();
        #pragma unroll
        for (int i = 0; i < 32; i += 8)
            nodesT[(long)(c0 + ty + i) * 2048 + r0 + tx] = f2b(t[tx][ty + i]);
    }
}

// v = sop0+sop1+bias (sop bf16); so_bf = bf16(v); partial sums of v^2.
__global__ __launch_bounds__(256) void bias_l2(const ushort* __restrict__ s,
        const float* __restrict__ bias, ushort* __restrict__ so_bf,
        float* __restrict__ partials) {
    __shared__ float red[256];
    const int tid = threadIdx.x;
    const long base = (long)blockIdx.x * 2048;
    float sum = 0.f;
    #pragma unroll
    for (int it = 0; it < 8; ++it) {
        const long i = base + tid + it * 256;
        const float v = b2f(s[i]) + b2f(s[i + 2097152]) + bias[i & 1023];
        so_bf[i] = f2b(v);
        sum += v * v;
    }
    red[tid] = sum;
    __syncthreads();
    #pragma unroll
    for (int w = 128; w > 0; w >>= 1) {
        if (tid < w) red[tid] += red[tid + w];
        __syncthreads();
    }
    if (tid == 0) partials[blockIdx.x] = red[0];
}

__global__ __launch_bounds__(256) void reduce_final(const float* __restrict__ partials,
                                                    float* __restrict__ out) {
    __shared__ float red[256];
    const int tid = threadIdx.x;
    red[tid] = partials[tid] + partials[tid + 256] + partials[tid + 512] + partials[tid + 768];
    __syncthreads();
    #pragma unroll
    for (int w = 128; w > 0; w >>= 1) {
        if (tid < w) red[tid] += red[tid + w];
        __syncthreads();
    }
    if (tid == 0) out[0] = red[0];
}

extern "C" void kernel_launch(void* const* d_in, const int* in_sizes, int n_in,
                              void* d_out, int out_size, void* d_ws, size_t ws_size,
                              hipStream_t stream) {
    const float* x   = (const float*)d_in[0];
    const float* lfw = (const float*)d_in[1];
    const float* inM = (const float*)d_in[2];
    const float* w3w = (const float*)d_in[3];
    const float* w3u = (const float*)d_in[4];
    const float* w4w = (const float*)d_in[5];
    const float* w4u = (const float*)d_in[6];
    const float* w5w = (const float*)d_in[7];
    const float* w5u = (const float*)d_in[8];
    const float* fcw = (const float*)d_in[9];
    const float* fcb = (const float*)d_in[10];
    float* out = (float*)d_out;

    const int B = 8192, N = 2048;
    const long NH = 2097152;

    ushort* zrp  = (ushort*)out;        // 2x [2048,2048] bf16 scratch
    ushort* hpre = (ushort*)out;        // 3x [2048,1024] bf16
    ushort* sop  = (ushort*)out;        // 2x [2048,1024] bf16

    char* p = (char*)d_ws;
    auto alloc = [&](size_t bytes) {
        char* r = p; p += (bytes + 255) & ~(size_t)255; return r;
    };
    float*  partials = (float*)alloc(1024 * 4);
    ushort* zv       = (ushort*)alloc(NH * 2);
    ushort* avn      = (ushort*)alloc(6291456ull * 2);
    ushort* nodesT   = (ushort*)alloc(NH * 2);
    ushort* ninit    = (ushort*)alloc(4194304ull * 2);
    ushort* inM_bf   = (ushort*)alloc(4194304ull * 2);
    ushort* inMT_bf  = (ushort*)alloc(4194304ull * 2);
    ushort* Wzr_t    = (ushort*)alloc(6291456ull * 2);
    ushort* W5_t     = (ushort*)alloc(3145728ull * 2);
    ushort* fcw_t    = (ushort*)alloc(NH * 2);
    ushort* x_bf     = (ushort*)alloc(8388608ull * 2);
    ushort* so_bf    = (ushort*)alloc(NH * 2);

    const dim3 tb(256);

    // ---- prep ----
    cvt_bf16_k<<<8192, tb, 0, stream>>>(x, x_bf, 2097152);
    inM_dual_k<<<dim3(64, 64), tb, 0, stream>>>(inM, inM_bf, inMT_bf);
    wprep_k<<<dim3(32, 64, 7), tb, 0, stream>>>(w3w, w4w, w5w, w3u, w4u, w5u,
                                                fcw, Wzr_t, W5_t, fcw_t);
    init_nodes_k<<<dim3(64, 32), tb, 0, stream>>>(lfw, nodesT, avn, ninit);

    // ---- GGNN time steps ----
    for (int t = 0; t < 3; ++t) {
        // avn[:, z*1024:+1024] = bf16( (z?inMT:inM) @ nodes ), direct epi
        gemm_t<2, 1><<<dim3(8, 32, 2), tb, 0, stream>>>(
            inM_bf, inMT_bf, nullptr, nodesT, avn,
            2048, 2048, 0, 2048, 3072,
            0, 0, 0, 1024, 1);
        // zr bf16 partials: split-K x2 over K=3072 (avn cols 2048:3072 = nodes)
        gemm_t<4, 1><<<dim3(16, 16, 2), tb, 0, stream>>>(
            avn, nullptr, nullptr, Wzr_t, zrp,
            1536, 3072, 0, 3072, 2048,
            1536, 0, 1536, 4194304, 2);
        // zv; rn overwrites avn cols 2048:3072 in-place
        gates_sum_k<<<2048, tb, 0, stream>>>(zrp, avn, zv);
        // hpre bf16 partials: 3-way zA split over avn cols (K=1024 each,
        // 768 blocks = 3/CU-capable)
        gemm_t<2, 1><<<dim3(8, 32, 3), tb, 0, stream>>>(
            avn, avn + 1024, avn + 2048, W5_t, hpre,
            1024, 3072, 3072, 3072, 1024,
            0, 1024, 0, 2097152, 1);
        if (t < 2)
            update_nodes_k<false><<<dim3(32, 64), tb, 0, stream>>>(
                zv, hpre, avn, ninit, nodesT);
        else
            update_nodes_k<true><<<dim3(32, 64), tb, 0, stream>>>(
                zv, hpre, avn, ninit, nodesT);
    }

    // step_out bf16 partials = [nodes|init] @ fc_out_w
    gemm_t<2, 1><<<dim3(8, 32, 2), tb, 0, stream>>>(
        ninit, ninit + 1024, nullptr, fcw_t, sop,
        1024, 2048, 0, 2048, 1024,
        0, 1024, 0, 2097152, 1);
    bias_l2<<<1024, tb, 0, stream>>>(sop, fcb, so_bf, partials);
    reduce_final<<<1, tb, 0, stream>>>(partials, out + (long)B * N);
    // output = x @ step_out^T : progressive 256x256 kernel
    gemm256b<<<dim3(8, 32), 512, 0, stream>>>(x_bf, so_bf, out,
                                              1024, 1024, 1024, 2048);
}